// Round 1
// baseline (352.574 us; speedup 1.0000x reference)
//
#include <hip/hip_runtime.h>

#define NBATCH 4
#define NROWS  100000
#define KD     16
#define EPSF   1e-6f
#define WCE    2.0f
#define WDICE  0.1f

#define THREADS 256
#define RPT     4                    // rows per thread
#define RPB     (THREADS * RPT)      // rows per block = 1024

// ws layout per batch (stride 576 floats):
// [0,256): P = sum v*(nlm-nl1m) at [i][j*]   (pos - Bcls combined)
// [256,512): I = sum v*m at [i][j*]
// [512,528): Bt[i] = sum v*nl1m
// [528,544): Sm[i] = sum v*m
// [544,560): Sg[j] = sum_{label=j} v
// [560]:     V = sum v
#define WSS 576

__global__ __launch_bounds__(THREADS) void sml_accum(
    const float* __restrict__ mask, const float* __restrict__ gt,
    const float* __restrict__ valid, float* __restrict__ ws)
{
  const int b  = blockIdx.y;
  const int n0 = blockIdx.x * RPB;

  __shared__ float sP[256];
  __shared__ float sI[256];
  __shared__ float sSg[16];

  sP[threadIdx.x] = 0.f;
  sI[threadIdx.x] = 0.f;
  if (threadIdx.x < 16) sSg[threadIdx.x] = 0.f;
  __syncthreads();

  float bt[KD], sm[KD];
#pragma unroll
  for (int i = 0; i < KD; ++i) { bt[i] = 0.f; sm[i] = 0.f; }
  float vsum = 0.f;

  const float* maskb  = mask  + (size_t)b * NROWS * KD;
  const float* gtb    = gt    + (size_t)b * NROWS * KD;
  const float* validb = valid + (size_t)b * NROWS;

  const int row0 = n0 + (int)threadIdx.x * RPT;

  float vv[RPT];
  if (row0 + RPT - 1 < NROWS) {
    const float4 v4 = *(const float4*)(validb + row0);
    vv[0] = v4.x; vv[1] = v4.y; vv[2] = v4.z; vv[3] = v4.w;
  } else {
#pragma unroll
    for (int r = 0; r < RPT; ++r) vv[r] = (row0 + r < NROWS) ? validb[row0 + r] : 0.f;
  }

#pragma unroll
  for (int r = 0; r < RPT; ++r) {
    const int n = row0 + r;
    if (n < NROWS) {
      const float v = vv[r];
      const float4* mrow = (const float4*)(maskb + (size_t)n * KD);
      const float4* grow = (const float4*)(gtb   + (size_t)n * KD);
      float m[KD], g[KD];
      {
        float4 q;
        q = mrow[0]; m[0]=q.x;  m[1]=q.y;  m[2]=q.z;  m[3]=q.w;
        q = mrow[1]; m[4]=q.x;  m[5]=q.y;  m[6]=q.z;  m[7]=q.w;
        q = mrow[2]; m[8]=q.x;  m[9]=q.y;  m[10]=q.z; m[11]=q.w;
        q = mrow[3]; m[12]=q.x; m[13]=q.y; m[14]=q.z; m[15]=q.w;
        q = grow[0]; g[0]=q.x;  g[1]=q.y;  g[2]=q.z;  g[3]=q.w;
        q = grow[1]; g[4]=q.x;  g[5]=q.y;  g[6]=q.z;  g[7]=q.w;
        q = grow[2]; g[8]=q.x;  g[9]=q.y;  g[10]=q.z; g[11]=q.w;
        q = grow[3]; g[12]=q.x; g[13]=q.y; g[14]=q.z; g[15]=q.w;
      }
      // one-hot -> label
      float jf = 0.f;
#pragma unroll
      for (int j = 0; j < KD; ++j) jf += g[j] * (float)j;
      const int js = (int)(jf + 0.5f);

      unsafeAtomicAdd(&sSg[js], v);
      vsum += v;

#pragma unroll
      for (int i = 0; i < KD; ++i) {
        const float mi   = m[i];
        const float mc   = fminf(fmaxf(mi, EPSF), 1.f - EPSF);
        const float nlm  = -__logf(mc);
        const float nl1m = -__logf(1.f - mc);
        bt[i] += v * nl1m;
        sm[i] += v * mi;
        unsafeAtomicAdd(&sP[i * KD + js], v * (nlm - nl1m));
        unsafeAtomicAdd(&sI[i * KD + js], v * mi);
      }
    }
  }

  float* wsb = ws + (size_t)b * WSS;
  const int lane = (int)threadIdx.x & 63;

  // wave-reduce register accumulators, one global atomic per wave
#pragma unroll
  for (int i = 0; i < KD; ++i) {
    float x = bt[i], y = sm[i];
#pragma unroll
    for (int off = 32; off > 0; off >>= 1) {
      x += __shfl_down(x, off);
      y += __shfl_down(y, off);
    }
    if (lane == 0) {
      unsafeAtomicAdd(&wsb[512 + i], x);
      unsafeAtomicAdd(&wsb[528 + i], y);
    }
  }
  {
    float x = vsum;
#pragma unroll
    for (int off = 32; off > 0; off >>= 1) x += __shfl_down(x, off);
    if (lane == 0) unsafeAtomicAdd(&wsb[560], x);
  }

  __syncthreads();
  unsafeAtomicAdd(&wsb[threadIdx.x], sP[threadIdx.x]);
  unsafeAtomicAdd(&wsb[256 + threadIdx.x], sI[threadIdx.x]);
  if (threadIdx.x < 16) unsafeAtomicAdd(&wsb[544 + threadIdx.x], sSg[threadIdx.x]);
}

// One wave: lanes = b*16 + col. Lane-parallel Jonker-Volgenant (e-maxx Hungarian),
// 16 lanes per batch hold column state, row duals live in the same lanes (lane r = u[row r]).
__global__ __launch_bounds__(64) void sml_solve(const float* __restrict__ ws,
                                                float* __restrict__ out)
{
  __shared__ float scost[NBATCH * 256];
  const int lane = (int)threadIdx.x;   // 0..63
  const int grp  = lane >> 4;          // batch
  const int col  = lane & 15;          // column index

  const float* wsb = ws + (size_t)grp * WSS;
  const float Vb = fmaxf(wsb[560], 1.f);
  const float sg = wsb[544 + col];

#pragma unroll
  for (int i = 0; i < KD; ++i) {
    const float P  = wsb[i * KD + col];
    const float In = wsb[256 + i * KD + col];
    const float Bt = wsb[512 + i];
    const float Sm = wsb[528 + i];
    const float ce = (P + Bt) / Vb;
    const float dc = 1.f - 2.f * In / (Sm + sg + EPSF);
    scost[grp * 256 + i * KD + col] = WCE * ce + WDICE * dc;
  }
  __syncthreads();

  float vdual = 0.f;   // v[col]
  float udual = 0.f;   // u[row == this lane's index-in-group]
  int   pcol  = -1;    // row assigned to this column (-1 = free)

  for (int i = 0; i < KD; ++i) {
    float minv   = 1e30f;
    int   way    = -1;          // tree predecessor column (-1 = virtual root)
    bool  used   = false;       // column in alternating tree
    bool  intree = (col == i);  // row (lane index) in alternating tree
    int   i0 = i;
    int   j0 = -1;

    for (int it = 0; it < 40; ++it) {
      const float u0   = __shfl(udual, i0, 16);
      const float aval = scost[grp * 256 + i0 * KD + col];
      const float cur  = aval - u0 - vdual;
      if (!used && cur < minv) { minv = cur; way = j0; }
      float cand = used ? 1e30f : minv;
      int   cidx = col;
#pragma unroll
      for (int off = 8; off > 0; off >>= 1) {
        const float oc = __shfl_xor(cand, off, 16);
        const int   oi = __shfl_xor(cidx, off, 16);
        if (oc < cand || (oc == cand && oi < cidx)) { cand = oc; cidx = oi; }
      }
      const float delta = cand;
      const int   j1    = cidx;
      if (used) vdual -= delta; else minv -= delta;
      if (intree) udual += delta;
      const int pj1 = __shfl(pcol, j1, 16);
      j0 = j1;
      if (pj1 < 0) break;              // free column found
      if (col == j1)  used   = true;
      if (col == pj1) intree = true;
      i0 = pj1;
    }

    // augment along way[] back to the virtual root
    int jcur = j0;
    for (int it = 0; it < 20; ++it) {
      const int w  = __shfl(way, jcur, 16);
      const int pw = (w >= 0) ? __shfl(pcol, w, 16) : i;
      if (col == jcur) pcol = pw;
      if (w < 0) break;
      jcur = w;
    }
  }

  // loss: each lane covers matched pair (row = pcol, col)
  const int ri = pcol;
  const float P  = wsb[ri * KD + col];
  const float Bt = wsb[512 + ri];
  const float In = wsb[256 + ri * KD + col];
  const float Sm = wsb[528 + ri];
  float c = P + Bt;                                   // CE numerator term
  float d = 1.f - 2.f * In / (Sm + sg + EPSF);        // dice term
#pragma unroll
  for (int off = 32; off > 0; off >>= 1) {
    c += __shfl_down(c, off);
    d += __shfl_down(d, off);
  }
  if (lane == 0) {
    float Vtot = ws[560] + ws[WSS + 560] + ws[2 * WSS + 560] + ws[3 * WSS + 560];
    Vtot = fmaxf(Vtot, 1.f);
    out[0] = WCE * c / (Vtot * (float)KD) + WDICE * d / 64.f;
  }
}

extern "C" void kernel_launch(void* const* d_in, const int* in_sizes, int n_in,
                              void* d_out, int out_size, void* d_ws, size_t ws_size,
                              hipStream_t stream)
{
  (void)in_sizes; (void)n_in; (void)out_size; (void)ws_size;
  const float* mask  = (const float*)d_in[0];
  const float* gt    = (const float*)d_in[1];
  const float* valid = (const float*)d_in[2];
  float* out = (float*)d_out;
  float* ws  = (float*)d_ws;

  hipMemsetAsync(d_ws, 0, NBATCH * WSS * sizeof(float), stream);

  dim3 grid((NROWS + RPB - 1) / RPB, NBATCH);
  sml_accum<<<grid, THREADS, 0, stream>>>(mask, gt, valid, ws);
  sml_solve<<<1, 64, 0, stream>>>(ws, out);
}

// Round 2
// 333.374 us; speedup vs baseline: 1.0576x; 1.0576x over previous
//
#include <hip/hip_runtime.h>

#define NBATCH 4
#define NROWS  100000
#define KD     16
#define EPSF   1e-6f
#define WCE    2.0f
#define WDICE  0.1f
#define NREP   8
#define BSTR   784   // per (rep,batch): N[256] | Q[256] | I[256] | Sg[16]

// ---------------- accumulation kernel ----------------
// Per row n with label js = argmax(gt), v = valid:
//   N[i][js] += v*(-log m_i)   Q[i][js] += v*(-log(1-m_i))   I[i][js] += v*m_i
//   Sg[js] += v
// Everything else (Bt, Sm, V, P) is derived in sml_solve by row sums.
__global__ __launch_bounds__(256) void sml_accum(
    const float* __restrict__ mask, const float* __restrict__ gt,
    const float* __restrict__ valid, float* __restrict__ ws)
{
  const int b   = blockIdx.y;
  const int tid = (int)threadIdx.x;
  __shared__ float sA[BSTR];
  for (int t = tid; t < BSTR; t += 256) sA[t] = 0.f;
  __syncthreads();

  const int n = blockIdx.x * 256 + tid;
  if (n < NROWS) {
    const float v = valid[(size_t)b * NROWS + n];
    if (v != 0.f) {
      const float4* mrow = (const float4*)(mask + ((size_t)b * NROWS + n) * KD);
      const float4* grow = (const float4*)(gt   + ((size_t)b * NROWS + n) * KD);
      float m[KD], g[KD];
      {
        float4 q;
        q = mrow[0]; m[0]=q.x;  m[1]=q.y;  m[2]=q.z;  m[3]=q.w;
        q = mrow[1]; m[4]=q.x;  m[5]=q.y;  m[6]=q.z;  m[7]=q.w;
        q = mrow[2]; m[8]=q.x;  m[9]=q.y;  m[10]=q.z; m[11]=q.w;
        q = mrow[3]; m[12]=q.x; m[13]=q.y; m[14]=q.z; m[15]=q.w;
        q = grow[0]; g[0]=q.x;  g[1]=q.y;  g[2]=q.z;  g[3]=q.w;
        q = grow[1]; g[4]=q.x;  g[5]=q.y;  g[6]=q.z;  g[7]=q.w;
        q = grow[2]; g[8]=q.x;  g[9]=q.y;  g[10]=q.z; g[11]=q.w;
        q = grow[3]; g[12]=q.x; g[13]=q.y; g[14]=q.z; g[15]=q.w;
      }
      float jf = 0.f;
#pragma unroll
      for (int j = 0; j < KD; ++j) jf += g[j] * (float)j;
      const int js = (int)(jf + 0.5f);

#pragma unroll
      for (int i = 0; i < KD; ++i) {
        const float mc   = fminf(fmaxf(m[i], EPSF), 1.f - EPSF);
        const float nlm  = -__logf(mc);
        const float nl1m = -__logf(1.f - mc);
        unsafeAtomicAdd(&sA[i * 16 + js],       v * nlm);
        unsafeAtomicAdd(&sA[256 + i * 16 + js], v * nl1m);
        unsafeAtomicAdd(&sA[512 + i * 16 + js], v * m[i]);
      }
      unsafeAtomicAdd(&sA[768 + js], v);
    }
  }
  __syncthreads();

  float* wsb = ws + ((size_t)(blockIdx.x & (NREP - 1)) * NBATCH + b) * BSTR;
  for (int t = tid; t < BSTR; t += 256) {
    const float x = sA[t];
    if (x != 0.f) unsafeAtomicAdd(&wsb[t], x);
  }
}

// ---------------- solve kernel ----------------
#define DPP_U(x, C) ((unsigned)__builtin_amdgcn_update_dpp(0, (int)(x), (C), 0xF, 0xF, true))

__device__ __forceinline__ float rowsum16(float x) {
  x += __uint_as_float(DPP_U(__float_as_uint(x), 0x128)); // ror 8
  x += __uint_as_float(DPP_U(__float_as_uint(x), 0x124)); // ror 4
  x += __uint_as_float(DPP_U(__float_as_uint(x), 0x122)); // ror 2
  x += __uint_as_float(DPP_U(__float_as_uint(x), 0x121)); // ror 1
  return x;
}
__device__ __forceinline__ unsigned rowmin16(unsigned x) {
  unsigned y;
  y = DPP_U(x, 0x128); x = (y < x) ? y : x;
  y = DPP_U(x, 0x124); x = (y < x) ? y : x;
  y = DPP_U(x, 0x122); x = (y < x) ? y : x;
  y = DPP_U(x, 0x121); x = (y < x) ? y : x;
  return x;
}
__device__ __forceinline__ float sel16f(const float* a, int idx) {
  float t8[8], t4[4], t2[2];
#pragma unroll
  for (int t = 0; t < 8; ++t) t8[t] = (idx & 1) ? a[2*t+1] : a[2*t];
#pragma unroll
  for (int t = 0; t < 4; ++t) t4[t] = (idx & 2) ? t8[2*t+1] : t8[2*t];
#pragma unroll
  for (int t = 0; t < 2; ++t) t2[t] = (idx & 4) ? t4[2*t+1] : t4[2*t];
  return (idx & 8) ? t2[1] : t2[0];
}
__device__ __forceinline__ int sel16i(const int* a, int idx) {
  int t8[8], t4[4], t2[2];
#pragma unroll
  for (int t = 0; t < 8; ++t) t8[t] = (idx & 1) ? a[2*t+1] : a[2*t];
#pragma unroll
  for (int t = 0; t < 4; ++t) t4[t] = (idx & 2) ? t8[2*t+1] : t8[2*t];
#pragma unroll
  for (int t = 0; t < 2; ++t) t2[t] = (idx & 4) ? t4[2*t+1] : t4[2*t];
  return (idx & 8) ? t2[1] : t2[0];
}

// One block, 4 waves; wave w solves batch w's 16x16 Hungarian on lanes 0-15
// (lane = column). Jonker-Volgenant as verified in round 1; cross-lane traffic
// replaced by DPP rotate-min + cndmask select trees. Row duals u[] replicated
// per-lane with deferred phase-end update (reads only ever see phase-start u).
__global__ __launch_bounds__(256) void sml_solve(const float* __restrict__ ws,
                                                 float* __restrict__ out)
{
  const int tid = (int)threadIdx.x;
  const int w   = tid >> 6;   // batch
  const int l   = tid & 63;
  __shared__ float part[NBATCH][3];

  if (l < 16) {
    const int col = l;
    float nc[16], qc[16], Ic[16];
    float Sg = 0.f;
#pragma unroll
    for (int i = 0; i < 16; ++i) { nc[i] = 0.f; qc[i] = 0.f; Ic[i] = 0.f; }
#pragma unroll
    for (int r = 0; r < NREP; ++r) {
      const float* wsb = ws + ((size_t)r * NBATCH + w) * BSTR;
#pragma unroll
      for (int i = 0; i < 16; ++i) {
        nc[i] += wsb[i * 16 + col];
        qc[i] += wsb[256 + i * 16 + col];
        Ic[i] += wsb[512 + i * 16 + col];
      }
      Sg += wsb[768 + col];
    }

    float Bt[16], Sm[16], Pc[16], a[16];
    const float V  = rowsum16(Sg);
    const float Vb = fmaxf(V, 1.f);
#pragma unroll
    for (int i = 0; i < 16; ++i) {
      Bt[i] = rowsum16(qc[i]);
      Sm[i] = rowsum16(Ic[i]);
      Pc[i] = nc[i] - qc[i];
      a[i]  = WCE * (Pc[i] + Bt[i]) / Vb
            + WDICE * (1.f - 2.f * Ic[i] / (Sm[i] + Sg + EPSF));
    }

    float u[16]; int p[16];
#pragma unroll
    for (int t = 0; t < 16; ++t) { u[t] = 0.f; p[t] = -1; }
    float v = 0.f;   // column dual (this lane's column)

    for (int i = 0; i < 16; ++i) {
      float au[16], Dent[16];
#pragma unroll
      for (int t = 0; t < 16; ++t) { au[t] = a[t] - u[t]; Dent[t] = 0.f; }
      float minv = 1e30f, D = 0.f;
      int way = -1, i0 = i, j0 = -1;
      bool used = false;
      unsigned treemask = 1u << i;

      for (int it = 0; it < 16; ++it) {
        const float cur = sel16f(au, i0) - v;
        if (!used && cur < minv) { minv = cur; way = j0; }
        const float cand = used ? 1e30f : minv;
        unsigned pk = (__float_as_uint(cand + 64.f) & 0xFFFFFFF0u) | (unsigned)col;
        pk = rowmin16(pk);
        const int   j1    = (int)(pk & 15u);
        const float delta = __uint_as_float(pk & 0xFFFFFFF0u) - 64.f;
        if (used) v -= delta; else minv -= delta;
        D += delta;
        const int pj1 = sel16i(p, j1);
        j0 = j1;
        if (pj1 < 0) break;               // free column found
        if (col == j1) used = true;
        treemask |= 1u << pj1;
#pragma unroll
        for (int t = 0; t < 16; ++t) if (t == pj1) Dent[t] = D;
        i0 = pj1;
      }
#pragma unroll
      for (int t = 0; t < 16; ++t)
        if ((treemask >> t) & 1u) u[t] += D - Dent[t];

      // augment along way[] back to the virtual root
      int jcur = j0;
      for (int s = 0; s < 17; ++s) {
        const int wy = __shfl(way, jcur, 64);   // way lives in lane jcur (0-15)
        const int pw = (wy >= 0) ? sel16i(p, wy) : i;
#pragma unroll
        for (int t = 0; t < 16; ++t) if (t == jcur) p[t] = pw;
        if (wy < 0) break;
        jcur = wy;
      }
    }

    // loss contributions: lane col matched with row ri
    const int ri = sel16i(p, col);
    float c = sel16f(Pc, ri) + sel16f(Bt, ri);
    float d = 1.f - 2.f * sel16f(Ic, ri) / (sel16f(Sm, ri) + Sg + EPSF);
    c = rowsum16(c);
    d = rowsum16(d);
    if (col == 0) { part[w][0] = c; part[w][1] = d; part[w][2] = V; }
  }
  __syncthreads();
  if (tid == 0) {
    float C = 0.f, Dd = 0.f, Vt = 0.f;
#pragma unroll
    for (int bb = 0; bb < NBATCH; ++bb) {
      C += part[bb][0]; Dd += part[bb][1]; Vt += part[bb][2];
    }
    Vt = fmaxf(Vt, 1.f);
    out[0] = WCE * C / (Vt * (float)KD) + WDICE * Dd / 64.f;
  }
}

extern "C" void kernel_launch(void* const* d_in, const int* in_sizes, int n_in,
                              void* d_out, int out_size, void* d_ws, size_t ws_size,
                              hipStream_t stream)
{
  (void)in_sizes; (void)n_in; (void)out_size; (void)ws_size;
  const float* mask  = (const float*)d_in[0];
  const float* gt    = (const float*)d_in[1];
  const float* valid = (const float*)d_in[2];
  float* out = (float*)d_out;
  float* ws  = (float*)d_ws;

  hipMemsetAsync(d_ws, 0, (size_t)NREP * NBATCH * BSTR * sizeof(float), stream);

  dim3 grid((NROWS + 255) / 256, NBATCH);
  sml_accum<<<grid, 256, 0, stream>>>(mask, gt, valid, ws);
  sml_solve<<<1, 256, 0, stream>>>(ws, out);
}

// Round 3
// 160.974 us; speedup vs baseline: 2.1903x; 2.0710x over previous
//
#include <hip/hip_runtime.h>

#define NBATCH 4
#define NROWS  100000
#define KD     16
#define EPSF   1e-6f
#define WCE    2.0f
#define WDICE  0.1f
#define NREP   8
#define LN2F   0.6931471805599453f

typedef __attribute__((ext_vector_type(8))) short short8;
typedef __attribute__((ext_vector_type(4))) float f32x4;

__device__ __forceinline__ unsigned short bf16rne(float x) {
  unsigned u = __float_as_uint(x);
  unsigned r = u + 0x7FFFu + ((u >> 16) & 1u);
  return (unsigned short)(r >> 16);
}

// ---------------- accumulation kernel (MFMA formulation) ----------------
// C[i][j] = sum_n A[n][i] * B[n][j]  with B[n][j] = v_n * gt[n][j] (one-hot):
//   P[i][j] = sum v*(-log m_i + log(1-m_i)) * g_j      (= N - Q)
//   Q[i][j] = sum v*(-log(1-m_i)) * g_j
//   I[i][j] = sum v*m_i * g_j
// Derived later: Bt[i]=sum_j Q, Sm[i]=sum_j I, Sg[j]=sum_i I (softmax rows sum
// to 1), V=sum Sg. No atomics in the hot loop; 12 global atomics per wave.
__global__ void sml_accum(const float* __restrict__ mask,
                          const float* __restrict__ gt,
                          const float* __restrict__ valid,
                          float* __restrict__ ws)
{
  const int b    = blockIdx.y;
  const int lane = (int)threadIdx.x & 63;
  const int wv   = (int)threadIdx.x >> 6;
  const int q    = lane >> 4;      // quad: k-slice 8q..8q+7
  const int c    = lane & 15;      // feature (A row m) / label (B col n)
  const int r0w  = blockIdx.x * 256 + wv * 64;   // wave's first row

  const float* maskb  = mask  + (size_t)b * NROWS * KD;
  const float* gtb    = gt    + (size_t)b * NROWS * KD;
  const float* validb = valid + (size_t)b * NROWS;

  f32x4 accP = {0.f, 0.f, 0.f, 0.f};
  f32x4 accQ = {0.f, 0.f, 0.f, 0.f};
  f32x4 accI = {0.f, 0.f, 0.f, 0.f};

#pragma unroll
  for (int ch = 0; ch < 2; ++ch) {
    const int rq = r0w + ch * 32 + 8 * q;   // this quad's first row
    float m[8], g[8], vv[8];
    if (rq + 7 < NROWS) {
      const float* mp = maskb + (size_t)rq * KD + c;
      const float* gp = gtb   + (size_t)rq * KD + c;
#pragma unroll
      for (int t = 0; t < 8; ++t) { m[t] = mp[(size_t)t * KD]; g[t] = gp[(size_t)t * KD]; }
      const float4 va = *(const float4*)(validb + rq);
      const float4 vb = *(const float4*)(validb + rq + 4);
      vv[0] = va.x; vv[1] = va.y; vv[2] = va.z; vv[3] = va.w;
      vv[4] = vb.x; vv[5] = vb.y; vv[6] = vb.z; vv[7] = vb.w;
    } else {
#pragma unroll
      for (int t = 0; t < 8; ++t) {
        const int r  = rq + t;
        const bool ok = (r < NROWS);
        const int rc = ok ? r : (NROWS - 1);
        m[t]  = maskb[(size_t)rc * KD + c];
        g[t]  = gtb[(size_t)rc * KD + c];
        vv[t] = ok ? validb[rc] : 0.f;
      }
    }
    short8 fP, fQ, fI, fB;
#pragma unroll
    for (int t = 0; t < 8; ++t) {
      const float mc = fminf(fmaxf(m[t], EPSF), 1.f - EPSF);
      const float lm = __log2f(mc);
      const float l1 = __log2f(1.f - mc);
      fP[t] = (short)bf16rne(LN2F * (l1 - lm));    // -log m + log(1-m)
      fQ[t] = (short)bf16rne(-LN2F * l1);          // -log(1-m)
      fI[t] = (short)bf16rne(m[t]);
      fB[t] = (short)bf16rne(vv[t] * g[t]);        // exact {0,1}
    }
    accP = __builtin_amdgcn_mfma_f32_16x16x32_bf16(fP, fB, accP, 0, 0, 0);
    accQ = __builtin_amdgcn_mfma_f32_16x16x32_bf16(fQ, fB, accQ, 0, 0, 0);
    accI = __builtin_amdgcn_mfma_f32_16x16x32_bf16(fI, fB, accI, 0, 0, 0);
  }

  // C/D layout: col = lane&15, row = (lane>>4)*4 + reg
  const int rep = (blockIdx.x * 4 + wv) & (NREP - 1);
  float* wsb = ws + ((size_t)rep * NBATCH + b) * 768;
#pragma unroll
  for (int r = 0; r < 4; ++r) {
    const int idx = (4 * q + r) * 16 + c;
    unsafeAtomicAdd(&wsb[idx],       accP[r]);
    unsafeAtomicAdd(&wsb[256 + idx], accQ[r]);
    unsafeAtomicAdd(&wsb[512 + idx], accI[r]);
  }
}

// ---------------- solve kernel ----------------
#define DPP_U(x, C) ((unsigned)__builtin_amdgcn_update_dpp(0, (int)(x), (C), 0xF, 0xF, true))

__device__ __forceinline__ float rowsum16(float x) {
  x += __uint_as_float(DPP_U(__float_as_uint(x), 0x128)); // row ror 8
  x += __uint_as_float(DPP_U(__float_as_uint(x), 0x124)); // row ror 4
  x += __uint_as_float(DPP_U(__float_as_uint(x), 0x122)); // row ror 2
  x += __uint_as_float(DPP_U(__float_as_uint(x), 0x121)); // row ror 1
  return x;
}
__device__ __forceinline__ unsigned rowmin16(unsigned x) {
  unsigned y;
  y = DPP_U(x, 0x128); x = (y < x) ? y : x;
  y = DPP_U(x, 0x124); x = (y < x) ? y : x;
  y = DPP_U(x, 0x122); x = (y < x) ? y : x;
  y = DPP_U(x, 0x121); x = (y < x) ? y : x;
  return x;
}

// select among 16 NAMED scalars (pass-by-value: cannot be demoted to memory)
__device__ __forceinline__ float sel16v(int idx,
  float x0, float x1, float x2, float x3, float x4, float x5, float x6, float x7,
  float x8, float x9, float x10, float x11, float x12, float x13, float x14, float x15)
{
  const float a0 = (idx & 1) ? x1  : x0;
  const float a1 = (idx & 1) ? x3  : x2;
  const float a2 = (idx & 1) ? x5  : x4;
  const float a3 = (idx & 1) ? x7  : x6;
  const float a4 = (idx & 1) ? x9  : x8;
  const float a5 = (idx & 1) ? x11 : x10;
  const float a6 = (idx & 1) ? x13 : x12;
  const float a7 = (idx & 1) ? x15 : x14;
  const float b0 = (idx & 2) ? a1 : a0;
  const float b1 = (idx & 2) ? a3 : a2;
  const float b2 = (idx & 2) ? a5 : a4;
  const float b3 = (idx & 2) ? a7 : a6;
  const float c0 = (idx & 4) ? b1 : b0;
  const float c1 = (idx & 4) ? b3 : b2;
  return (idx & 8) ? c1 : c0;
}

#define R16(M) M(0) M(1) M(2) M(3) M(4) M(5) M(6) M(7) M(8) M(9) M(10) M(11) M(12) M(13) M(14) M(15)
#define SEL16(p, idx) sel16v(idx, p##0,p##1,p##2,p##3,p##4,p##5,p##6,p##7,p##8,p##9,p##10,p##11,p##12,p##13,p##14,p##15)

#define DECL3(i) float qc##i = 0.f, ic##i = 0.f, pc##i = 0.f;
#define ACCR(i)  pc##i += base[i*16]; qc##i += base[256 + i*16]; ic##i += base[512 + i*16];
#define SGQS(i)  sg += ic##i; qs += qc##i;
#define MKA(i)   const float Sm##i = rowsum16(ic##i); \
  const float a##i = WCE * (pc##i + rowsum16(qc##i)) / Vb \
                   + WDICE * (1.f - 2.f * ic##i / (Sm##i + sg + EPSF));
#define DECLU(i) float u##i = 0.f;
#define UPDU(i)  u##i += ((treemask >> i) & 1u) ? delta : 0.f;

// 4 waves, wave w = batch w, lanes 0-15 (lane = column). Jonker-Volgenant with
// the round-1-verified recurrence; all dynamic-index state in named registers
// (select trees) or wave-uniform packed nibbles (shifts). No private arrays.
__global__ __launch_bounds__(256) void sml_solve(const float* __restrict__ ws,
                                                 float* __restrict__ out)
{
  const int tid = (int)threadIdx.x;
  const int w   = tid >> 6;
  const int l   = tid & 63;
  __shared__ float part[NBATCH][3];

  if (l < 16) {
    const int col = l;
    R16(DECL3)
    for (int r = 0; r < NREP; ++r) {
      const float* base = ws + ((size_t)r * NBATCH + w) * 768 + col;
      R16(ACCR)
    }
    float sg = 0.f, qs = 0.f;
    R16(SGQS)
    const float V    = rowsum16(sg);
    const float Vb   = fmaxf(V, 1.f);
    const float Btot = rowsum16(qs);   // sum_i Bt[i] = sum_ij Q
    R16(MKA)

    float vdual = 0.f;
    R16(DECLU)
    unsigned long long pword = 0ull;   // nibble j = row assigned to col j (wave-uniform)
    unsigned pmask = 0u;               // bit j = col j assigned

    for (int i = 0; i < 16; ++i) {
      float minv = 1e30f;
      int   way  = -1;                 // per-lane: tree predecessor of this col
      bool  used = false;
      unsigned treemask = 1u << i;
      int i0 = i, j0 = -1;

      for (int it = 0; it < 17; ++it) {
        const float cur = SEL16(a, i0) - SEL16(u, i0) - vdual;
        if (!used && cur < minv) { minv = cur; way = j0; }
        unsigned pk = (__float_as_uint((used ? 1e30f : minv) + 64.f) & 0xFFFFFFF0u)
                    | (unsigned)col;
        pk = rowmin16(pk);
        const int   j1    = (int)(pk & 15u);
        const float delta = __uint_as_float(pk & 0xFFFFFFF0u) - 64.f;
        if (used) vdual -= delta; else minv -= delta;
        R16(UPDU)
        j0 = j1;
        const int  pj1 = (int)((pword >> (4 * j1)) & 15ull);
        const bool asg = (pmask >> j1) & 1u;
        if (!asg) break;               // free column found
        if (col == j1) used = true;
        treemask |= 1u << pj1;
        i0 = pj1;
      }

      // augment: p[jcur] <- p[way[jcur]] back to the virtual root
      int jcur = j0;
      for (int s = 0; s < 17; ++s) {
        const int wy   = __shfl(way, jcur, 64);
        const int prev = (wy >= 0) ? (int)((pword >> (4 * wy)) & 15ull) : i;
        pword = (pword & ~(15ull << (4 * jcur)))
              | ((unsigned long long)prev << (4 * jcur));
        pmask |= 1u << jcur;
        if (wy < 0) break;
        jcur = wy;
      }
    }

    // loss: lane col is matched with row ri. CE numerator = sum_matched P + Btot.
    const int ri = (int)((pword >> (4 * col)) & 15ull);
    float pcm = 0.f, icm = 0.f;
    for (int r = 0; r < NREP; ++r) {
      const float* base = ws + ((size_t)r * NBATCH + w) * 768;
      pcm += base[ri * 16 + col];
      icm += base[512 + ri * 16 + col];
    }
    const float smv = SEL16(Sm, ri);
    const float cce = rowsum16(pcm);
    const float dce = rowsum16(1.f - 2.f * icm / (smv + sg + EPSF));
    if (col == 0) { part[w][0] = cce + Btot; part[w][1] = dce; part[w][2] = V; }
  }
  __syncthreads();

  if (tid == 0) {
    float C = 0.f, D = 0.f, Vt = 0.f;
#pragma unroll
    for (int bb = 0; bb < NBATCH; ++bb) {
      C += part[bb][0]; D += part[bb][1]; Vt += part[bb][2];
    }
    Vt = fmaxf(Vt, 1.f);
    out[0] = WCE * C / (Vt * (float)KD) + WDICE * D / 64.f;
  }
}

extern "C" void kernel_launch(void* const* d_in, const int* in_sizes, int n_in,
                              void* d_out, int out_size, void* d_ws, size_t ws_size,
                              hipStream_t stream)
{
  (void)in_sizes; (void)n_in; (void)out_size; (void)ws_size;
  const float* mask  = (const float*)d_in[0];
  const float* gt    = (const float*)d_in[1];
  const float* valid = (const float*)d_in[2];
  float* out = (float*)d_out;
  float* ws  = (float*)d_ws;

  hipMemsetAsync(d_ws, 0, (size_t)NREP * NBATCH * 768 * sizeof(float), stream);

  dim3 grid((NROWS + 255) / 256, NBATCH);
  sml_accum<<<grid, 256, 0, stream>>>(mask, gt, valid, ws);
  sml_solve<<<1, 256, 0, stream>>>(ws, out);
}

// Round 4
// 150.619 us; speedup vs baseline: 2.3408x; 1.0687x over previous
//
#include <hip/hip_runtime.h>

#define NBATCH 4
#define NROWS  100000
#define KD     16
#define EPSF   1e-6f
#define WCE    2.0f
#define WDICE  0.1f
#define NREP   8
#define LN2F   0.6931471805599453f

typedef __attribute__((ext_vector_type(8))) short short8;
typedef __attribute__((ext_vector_type(4))) float f32x4;

__device__ __forceinline__ unsigned short bf16rne(float x) {
  unsigned u = __float_as_uint(x);
  unsigned r = u + 0x7FFFu + ((u >> 16) & 1u);
  return (unsigned short)(r >> 16);
}

__device__ __forceinline__ void async_copy16(const float* g, float* l) {
  __builtin_amdgcn_global_load_lds(
      (const __attribute__((address_space(1))) float*)g,
      (__attribute__((address_space(3))) float*)l, 16, 0, 0);
}

// ---------------- accumulation kernel (MFMA + LDS staging) ----------------
// C[i][j] = sum_n A[n][i] * B[n][j], B[n][j] = v_n * gt[n][j] (one-hot):
//   P[i][j]=sum v*(-log m + log(1-m))*g,  Q[i][j]=sum v*(-log(1-m))*g,
//   I[i][j]=sum v*m*g.  Derived in solve: Bt=rowsum Q, Sm=rowsum I,
//   Sg=colsum I (softmax rows sum to 1), V=sum Sg.
// Staging: global_load_lds width=16 into 32KB LDS (lane-contiguous, no pad);
// fragment gather = ds_read_b32 at 4-way bank alias (~1.58x, acceptable).
__global__ __launch_bounds__(256) void sml_accum(
    const float* __restrict__ mask, const float* __restrict__ gt,
    const float* __restrict__ valid, float* __restrict__ ws)
{
  const int b    = blockIdx.y;
  const int tid  = (int)threadIdx.x;
  const int lane = tid & 63;
  const int wv   = tid >> 6;
  const int q    = lane >> 4;      // quad: k-slice rows 8q..8q+7
  const int c    = lane & 15;      // feature / label column
  const int row0 = blockIdx.x * 256;

  __shared__ float sM[4096];       // 256 rows x 16 cols, row-major (memory order)
  __shared__ float sG[4096];

  const float* maskb  = mask  + (size_t)b * NROWS * KD;
  const float* gtb    = gt    + (size_t)b * NROWS * KD;
  const float* validb = valid + (size_t)b * NROWS;

#pragma unroll
  for (int i = 0; i < 4; ++i) {
    const int idx = i * 256 + tid;            // 16B chunk index in tile
    const int rg  = row0 + (idx >> 2);        // global row of this chunk
    const int rc  = (rg < NROWS) ? rg : (NROWS - 1);   // clamp tail (finite data)
    const size_t off = (size_t)rc * KD + (size_t)(idx & 3) * 4;
    async_copy16(maskb + off, &sM[idx * 4]);
    async_copy16(gtb   + off, &sG[idx * 4]);
  }
  __syncthreads();   // compiler drains vmcnt before s_barrier

  f32x4 accP = {0.f, 0.f, 0.f, 0.f};
  f32x4 accQ = {0.f, 0.f, 0.f, 0.f};
  f32x4 accI = {0.f, 0.f, 0.f, 0.f};

#pragma unroll
  for (int ch = 0; ch < 2; ++ch) {
    const int rt = wv * 64 + ch * 32 + 8 * q;     // tile row of this quad
    float m[8], g[8], vv[8];
#pragma unroll
    for (int t = 0; t < 8; ++t) {
      m[t] = sM[(rt + t) * 16 + c];
      g[t] = sG[(rt + t) * 16 + c];
    }
    const int grow = row0 + rt;
    if (grow + 7 < NROWS) {
      const float4 va = *(const float4*)(validb + grow);
      const float4 vb4 = *(const float4*)(validb + grow + 4);
      vv[0] = va.x; vv[1] = va.y; vv[2] = va.z; vv[3] = va.w;
      vv[4] = vb4.x; vv[5] = vb4.y; vv[6] = vb4.z; vv[7] = vb4.w;
    } else {
#pragma unroll
      for (int t = 0; t < 8; ++t)
        vv[t] = (grow + t < NROWS) ? validb[grow + t] : 0.f;
    }

    short8 fP, fQ, fI, fB;
#pragma unroll
    for (int t = 0; t < 8; ++t) {
      const float mc = fminf(fmaxf(m[t], EPSF), 1.f - EPSF);
      const float lm = __log2f(mc);
      const float l1 = __log2f(1.f - mc);
      fP[t] = (short)bf16rne(LN2F * (l1 - lm));
      fQ[t] = (short)bf16rne(-LN2F * l1);
      fI[t] = (short)bf16rne(m[t]);
      fB[t] = (short)bf16rne(vv[t] * g[t]);     // exact {0,1}
    }
    accP = __builtin_amdgcn_mfma_f32_16x16x32_bf16(fP, fB, accP, 0, 0, 0);
    accQ = __builtin_amdgcn_mfma_f32_16x16x32_bf16(fQ, fB, accQ, 0, 0, 0);
    accI = __builtin_amdgcn_mfma_f32_16x16x32_bf16(fI, fB, accI, 0, 0, 0);
  }

  // C/D layout: col = lane&15, row = (lane>>4)*4 + reg
  const int rep = (blockIdx.x * 4 + wv) & (NREP - 1);
  float* wsb = ws + ((size_t)rep * NBATCH + b) * 768;
#pragma unroll
  for (int r = 0; r < 4; ++r) {
    const int idx = (4 * q + r) * 16 + c;
    unsafeAtomicAdd(&wsb[idx],       accP[r]);
    unsafeAtomicAdd(&wsb[256 + idx], accQ[r]);
    unsafeAtomicAdd(&wsb[512 + idx], accI[r]);
  }
}

// ---------------- solve kernel ----------------
#define DPP_U(x, C) ((unsigned)__builtin_amdgcn_update_dpp(0, (int)(x), (C), 0xF, 0xF, true))

__device__ __forceinline__ float rowsum16(float x) {
  x += __uint_as_float(DPP_U(__float_as_uint(x), 0x128)); // row ror 8
  x += __uint_as_float(DPP_U(__float_as_uint(x), 0x124)); // row ror 4
  x += __uint_as_float(DPP_U(__float_as_uint(x), 0x122)); // row ror 2
  x += __uint_as_float(DPP_U(__float_as_uint(x), 0x121)); // row ror 1
  return x;
}
__device__ __forceinline__ unsigned rowmin16(unsigned x) {
  unsigned y;
  y = DPP_U(x, 0x128); x = (y < x) ? y : x;
  y = DPP_U(x, 0x124); x = (y < x) ? y : x;
  y = DPP_U(x, 0x122); x = (y < x) ? y : x;
  y = DPP_U(x, 0x121); x = (y < x) ? y : x;
  return x;
}
__device__ __forceinline__ float readlane_f(float x, int l) {
  return __int_as_float(__builtin_amdgcn_readlane(__float_as_int(x), l));
}

__device__ __forceinline__ float sel16v(int idx,
  float x0, float x1, float x2, float x3, float x4, float x5, float x6, float x7,
  float x8, float x9, float x10, float x11, float x12, float x13, float x14, float x15)
{
  const float a0 = (idx & 1) ? x1  : x0;
  const float a1 = (idx & 1) ? x3  : x2;
  const float a2 = (idx & 1) ? x5  : x4;
  const float a3 = (idx & 1) ? x7  : x6;
  const float a4 = (idx & 1) ? x9  : x8;
  const float a5 = (idx & 1) ? x11 : x10;
  const float a6 = (idx & 1) ? x13 : x12;
  const float a7 = (idx & 1) ? x15 : x14;
  const float b0 = (idx & 2) ? a1 : a0;
  const float b1 = (idx & 2) ? a3 : a2;
  const float b2 = (idx & 2) ? a5 : a4;
  const float b3 = (idx & 2) ? a7 : a6;
  const float c0 = (idx & 4) ? b1 : b0;
  const float c1 = (idx & 4) ? b3 : b2;
  return (idx & 8) ? c1 : c0;
}

#define R16(M) M(0) M(1) M(2) M(3) M(4) M(5) M(6) M(7) M(8) M(9) M(10) M(11) M(12) M(13) M(14) M(15)
#define SEL16(p, idx) sel16v(idx, p##0,p##1,p##2,p##3,p##4,p##5,p##6,p##7,p##8,p##9,p##10,p##11,p##12,p##13,p##14,p##15)

#define DECL3(i) float qc##i = 0.f, ic##i = 0.f, pc##i = 0.f;
#define ACCR(i)  pc##i += base[i*16]; qc##i += base[256 + i*16]; ic##i += base[512 + i*16];
#define SGQS(i)  sg += ic##i; qs += qc##i;
#define MKA(i)   const float Sm##i = rowsum16(ic##i); \
  const float a##i = WCE * (pc##i + rowsum16(qc##i)) / Vb \
                   + WDICE * (1.f - 2.f * ic##i / (Sm##i + sg + EPSF));

// 4 waves, wave w = batch w, lanes 0-15. lane l holds col-l state (a,minv,way,
// used,vdual) AND row-l state (u,Dent,intree). Wave-uniform tree bookkeeping
// (i0, pword, pmask, jcur) stays scalar; uniform-index reads use v_readlane.
// Same JV recurrence as rounds 1-3 (absmax 0.0): reads of u[i0] always see
// phase-start values, so per-iteration u updates are replaced by per-lane
// entry stamps (Dent) + one phase-end update.
__global__ __launch_bounds__(256) void sml_solve(const float* __restrict__ ws,
                                                 float* __restrict__ out)
{
  const int tid = (int)threadIdx.x;
  const int w   = tid >> 6;
  const int l   = tid & 63;
  __shared__ float part[NBATCH][3];

  if (l < 16) {
    const int col = l;
    R16(DECL3)
    for (int r = 0; r < NREP; ++r) {
      const float* base = ws + ((size_t)r * NBATCH + w) * 768 + col;
      R16(ACCR)
    }
    float sg = 0.f, qs = 0.f;
    R16(SGQS)
    const float V    = rowsum16(sg);
    const float Vb   = fmaxf(V, 1.f);
    const float Btot = rowsum16(qs);
    R16(MKA)

    float vdual = 0.f;
    float u_t   = 0.f;                  // u[row = lane]
    unsigned long long pword = 0ull;    // nibble j = row assigned to col j (uniform)
    unsigned pmask = 0u;                // bit j = col j assigned (uniform)

    for (int i = 0; i < 16; ++i) {
      float minv = 1e30f;
      int   way  = -1;                  // per-lane: tree predecessor of this col
      bool  used = false;
      float Dent = 0.f;                 // per-lane: cumulative delta at row entry
      float Dcum = 0.f;
      bool  intree = (col == i);        // row(lane) in tree; root = i
      int   i0 = i;                     // uniform
      int   j0 = -1;                    // uniform

      for (int it = 0; it < 17; ++it) {
        const float u0  = readlane_f(u_t, i0);
        const float cur = SEL16(a, i0) - u0 - vdual;
        if (!used && cur < minv) { minv = cur; way = j0; }
        unsigned pk = (__float_as_uint((used ? 1e30f : minv) + 64.f) & 0xFFFFFFF0u)
                    | (unsigned)col;
        pk = rowmin16(pk);
        const float delta = __uint_as_float(pk & 0xFFFFFFF0u) - 64.f;
        if (used) vdual -= delta; else minv -= delta;
        Dcum += delta;
        const int j1s = __builtin_amdgcn_readfirstlane((int)(pk & 15u));
        const int  pj1 = (int)((pword >> (4 * j1s)) & 15ull);
        const bool asg = (pmask >> j1s) & 1u;
        j0 = j1s;
        if (!asg) break;                // free column found
        used   = used   || (col == j1s);
        Dent   = (col == pj1) ? Dcum : Dent;   // row pj1 stamps its entry D
        intree = intree || (col == pj1);
        i0 = pj1;
      }
      u_t += intree ? (Dcum - Dent) : 0.f;     // phase-end row-dual update

      // augment along way[] back to the virtual root (all scalar + readlane)
      int jcur = j0;
      for (int s = 0; s < 17; ++s) {
        const int wy   = __builtin_amdgcn_readlane(way, jcur);
        const int prev = (wy >= 0) ? (int)((pword >> (4 * wy)) & 15ull) : i;
        pword = (pword & ~(15ull << (4 * jcur)))
              | ((unsigned long long)prev << (4 * jcur));
        pmask |= 1u << jcur;
        if (wy < 0) break;
        jcur = wy;
      }
    }

    // loss: lane col matched with row ri. CE numerator = sum_matched P + Btot.
    const int ri = (int)((pword >> (4 * col)) & 15ull);
    float pcm = 0.f, icm = 0.f;
    for (int r = 0; r < NREP; ++r) {
      const float* base = ws + ((size_t)r * NBATCH + w) * 768;
      pcm += base[ri * 16 + col];
      icm += base[512 + ri * 16 + col];
    }
    const float smv = SEL16(Sm, ri);
    const float cce = rowsum16(pcm);
    const float dce = rowsum16(1.f - 2.f * icm / (smv + sg + EPSF));
    if (col == 0) { part[w][0] = cce + Btot; part[w][1] = dce; part[w][2] = V; }
  }
  __syncthreads();

  if (tid == 0) {
    float C = 0.f, D = 0.f, Vt = 0.f;
#pragma unroll
    for (int bb = 0; bb < NBATCH; ++bb) {
      C += part[bb][0]; D += part[bb][1]; Vt += part[bb][2];
    }
    Vt = fmaxf(Vt, 1.f);
    out[0] = WCE * C / (Vt * (float)KD) + WDICE * D / 64.f;
  }
}

extern "C" void kernel_launch(void* const* d_in, const int* in_sizes, int n_in,
                              void* d_out, int out_size, void* d_ws, size_t ws_size,
                              hipStream_t stream)
{
  (void)in_sizes; (void)n_in; (void)out_size; (void)ws_size;
  const float* mask  = (const float*)d_in[0];
  const float* gt    = (const float*)d_in[1];
  const float* valid = (const float*)d_in[2];
  float* out = (float*)d_out;
  float* ws  = (float*)d_ws;

  hipMemsetAsync(d_ws, 0, (size_t)NREP * NBATCH * 768 * sizeof(float), stream);

  dim3 grid((NROWS + 255) / 256, NBATCH);
  sml_accum<<<grid, 256, 0, stream>>>(mask, gt, valid, ws);
  sml_solve<<<1, 256, 0, stream>>>(ws, out);
}